// Round 2
// baseline (206.108 us; speedup 1.0000x reference)
//
#include <hip/hip_runtime.h>

// Problem constants (from reference): B=64, C=512, H=W=32, N=1, A=16
#define B_DIM 64
#define C_DIM 512
#define A_DIM 16
#define HW    1024           // H*W
#define EPS   1e-5f

// ---------------------------------------------------------------------------
// Kernel 1: per-(b,c) row reduction of x (contiguous 1024 floats each).
// 8 rows per block (4 waves x 2 rows/wave); each lane loads 8 float4s up
// front (128 B in flight) for memory-level parallelism; wave shuffle-reduce
// only (no LDS / __syncthreads). Writes interleaved (sum, sumsq) as float2
// at sums[c*B + b] so kernel 2 reads one coalesced float2 per lane.
// ---------------------------------------------------------------------------
__global__ __launch_bounds__(256) void reduce_rows(const float* __restrict__ x,
                                                   float2* __restrict__ sums) {
    const int wave = threadIdx.x >> 6;
    const int lane = threadIdx.x & 63;
    const int rowA = blockIdx.x * 8 + wave * 2;      // row = b*C + c
    const int rowB = rowA + 1;
    const float4* pA = reinterpret_cast<const float4*>(x) + (size_t)rowA * 256;
    const float4* pB = reinterpret_cast<const float4*>(x) + (size_t)rowB * 256;
    // issue all 8 loads before any use
    const float4 a0 = pA[lane];
    const float4 a1 = pA[lane + 64];
    const float4 a2 = pA[lane + 128];
    const float4 a3 = pA[lane + 192];
    const float4 b0 = pB[lane];
    const float4 b1 = pB[lane + 64];
    const float4 b2 = pB[lane + 128];
    const float4 b3 = pB[lane + 192];

    float sA = (a0.x + a0.y + a0.z + a0.w) + (a1.x + a1.y + a1.z + a1.w)
             + (a2.x + a2.y + a2.z + a2.w) + (a3.x + a3.y + a3.z + a3.w);
    float qA = (a0.x * a0.x + a0.y * a0.y + a0.z * a0.z + a0.w * a0.w)
             + (a1.x * a1.x + a1.y * a1.y + a1.z * a1.z + a1.w * a1.w)
             + (a2.x * a2.x + a2.y * a2.y + a2.z * a2.z + a2.w * a2.w)
             + (a3.x * a3.x + a3.y * a3.y + a3.z * a3.z + a3.w * a3.w);
    float sB = (b0.x + b0.y + b0.z + b0.w) + (b1.x + b1.y + b1.z + b1.w)
             + (b2.x + b2.y + b2.z + b2.w) + (b3.x + b3.y + b3.z + b3.w);
    float qB = (b0.x * b0.x + b0.y * b0.y + b0.z * b0.z + b0.w * b0.w)
             + (b1.x * b1.x + b1.y * b1.y + b1.z * b1.z + b1.w * b1.w)
             + (b2.x * b2.x + b2.y * b2.y + b2.z * b2.z + b2.w * b2.w)
             + (b3.x * b3.x + b3.y * b3.y + b3.z * b3.z + b3.w * b3.w);

#pragma unroll
    for (int off = 32; off > 0; off >>= 1) {
        sA += __shfl_down(sA, off);
        qA += __shfl_down(qA, off);
        sB += __shfl_down(sB, off);
        qB += __shfl_down(qB, off);
    }
    if (lane == 0) {
        int b = rowA >> 9, c = rowA & (C_DIM - 1);
        sums[c * B_DIM + b] = make_float2(sA, qA);
        b = rowB >> 9;  c = rowB & (C_DIM - 1);
        sums[c * B_DIM + b] = make_float2(sB, qB);
    }
}

// ---------------------------------------------------------------------------
// Kernel 2: blocks [0,512): per-channel batch stats + new_x.
//           blocks [512,528): LayerNorm of router_weights^T rows -> wn_t[c][a].
// 64 threads = 1 wave per block.
// ---------------------------------------------------------------------------
__global__ __launch_bounds__(64) void stats_newx_ln(
    const float2* __restrict__ sums,
    const float* __restrict__ bn_g, const float* __restrict__ bn_b,
    const float* __restrict__ rw, const float* __restrict__ ln_g,
    const float* __restrict__ ln_b,
    float* __restrict__ newx, float* __restrict__ wn_t) {
    const int lane = threadIdx.x;
    if (blockIdx.x < C_DIM) {
        // --- batch-norm stats for channel c + pooled new_x ---
        const int c = blockIdx.x;
        const float2 t = sums[c * B_DIM + lane];     // lane == b
        float ts = t.x, tq = t.y;
#pragma unroll
        for (int off = 32; off > 0; off >>= 1) {
            ts += __shfl_down(ts, off);
            tq += __shfl_down(tq, off);
        }
        const float mu  = __shfl(ts, 0) * (1.0f / 65536.0f);   // /(B*H*W)
        const float var = __shfl(tq, 0) * (1.0f / 65536.0f) - mu * mu;
        const float r   = rsqrtf(var + EPS);
        const float nx  = bn_g[c] * (t.x * (1.0f / 1024.0f) - mu) * r + bn_b[c];
        newx[lane * C_DIM + c] = nx;                 // new_x[b][c]
    } else {
        // --- LayerNorm over C of router_weights[:,a] (i.e. W^T row a) ---
        const int a = blockIdx.x - C_DIM;
        float wv[8];
        float s = 0.f, q = 0.f;
#pragma unroll
        for (int j = 0; j < 8; j++) {
            const int c = j * 64 + lane;
            wv[j] = rw[c * A_DIM + a];
            s += wv[j];
            q += wv[j] * wv[j];
        }
#pragma unroll
        for (int off = 32; off > 0; off >>= 1) {
            s += __shfl_down(s, off);
            q += __shfl_down(q, off);
        }
        const float m = __shfl(s, 0) * (1.0f / 512.0f);
        const float v = __shfl(q, 0) * (1.0f / 512.0f) - m * m;
        const float r = rsqrtf(v + EPS);
#pragma unroll
        for (int j = 0; j < 8; j++) {
            const int c = j * 64 + lane;
            wn_t[c * A_DIM + a] = (wv[j] - m) * r * ln_g[c] + ln_b[c];  // [c][a]
        }
    }
}

// ---------------------------------------------------------------------------
// Kernel 3: logits[b][a] = new_x[b,:] . wn[:,a] + bias[a]; softmax over a.
// One block per b; 64 lanes: lane = a + 16*chunk, each lane does 128 MACs,
// combine chunks via shfl_xor(16|32), softmax within 16-lane subgroups.
// ---------------------------------------------------------------------------
__global__ __launch_bounds__(64) void matmul_softmax(
    const float* __restrict__ newx, const float* __restrict__ wn_t,
    const float* __restrict__ rbias,
    float* __restrict__ logits, float* __restrict__ probs) {
    const int b = blockIdx.x;
    const int lane = threadIdx.x;
    const int a = lane & 15;
    const int chunk = lane >> 4;
    const float* xr = newx + b * C_DIM + chunk * 128;
    const float* wr = wn_t + (chunk * 128) * A_DIM + a;
    float acc = 0.f;
#pragma unroll 8
    for (int i = 0; i < 128; i++) {
        acc += xr[i] * wr[i * A_DIM];
    }
    acc += __shfl_xor(acc, 16);
    acc += __shfl_xor(acc, 32);
    const float logit = acc + rbias[a];
    float mx = logit;
#pragma unroll
    for (int m = 1; m < 16; m <<= 1) mx = fmaxf(mx, __shfl_xor(mx, m));
    const float e = expf(logit - mx);
    float se = e;
#pragma unroll
    for (int m = 1; m < 16; m <<= 1) se += __shfl_xor(se, m);
    const float prob = e / se;
    if (lane < 16) {                                 // lane == a here
        logits[b * A_DIM + lane] = logit;
        probs[b * A_DIM + lane] = prob;
    }
}

extern "C" void kernel_launch(void* const* d_in, const int* in_sizes, int n_in,
                              void* d_out, int out_size, void* d_ws, size_t ws_size,
                              hipStream_t stream) {
    const float* x     = (const float*)d_in[0];   // [B,C,H,W]
    const float* rw    = (const float*)d_in[1];   // [1,C,A]
    const float* rbias = (const float*)d_in[2];   // [1,A]
    const float* bn_g  = (const float*)d_in[3];   // [1,C]
    const float* bn_b  = (const float*)d_in[4];
    const float* ln_g  = (const float*)d_in[5];
    const float* ln_b  = (const float*)d_in[6];

    float* out    = (float*)d_out;
    float* newx   = out;                          // 32768 floats: new_x [1,64,512]
    float* logits = out + B_DIM * C_DIM;          // 1024 floats
    float* probs  = logits + B_DIM * A_DIM;       // 1024 floats

    float2* sums = (float2*)d_ws;                 // 32768 float2  [c][b] (sum, sumsq)
    float*  wn_t = (float*)(sums + B_DIM * C_DIM); // 8192 floats  [c][a]

    reduce_rows<<<(B_DIM * C_DIM) / 8, 256, 0, stream>>>(x, sums);
    stats_newx_ln<<<C_DIM + A_DIM, 64, 0, stream>>>(sums, bn_g, bn_b, rw,
                                                    ln_g, ln_b, newx, wn_t);
    matmul_softmax<<<B_DIM, 64, 0, stream>>>(newx, wn_t, rbias, logits, probs);
}